// Round 4
// baseline (988.427 us; speedup 1.0000x reference)
//
#include <hip/hip_runtime.h>
#include <cstddef>

#define NBATCH 8
#define NCH 512
#define NTOK 4096   // 64*64 tokens
#define NH 8
#define HD 64
#define QKV_M 1536
#define LN_EPS 1e-5f

typedef unsigned short bf16_t;

__device__ __forceinline__ float bf2f(bf16_t u) {
    return __uint_as_float(((unsigned)u) << 16);
}
// round-to-nearest-even fp32 -> bf16, packed pair (a in low half, b in high)
__device__ __forceinline__ unsigned pack2bf(float a, float b) {
    unsigned ua = __float_as_uint(a);
    ua += 0x7FFFu + ((ua >> 16) & 1u);
    unsigned ub = __float_as_uint(b);
    ub += 0x7FFFu + ((ub >> 16) & 1u);
    return (ua >> 16) | (ub & 0xFFFF0000u);
}

// ---------------- LN stats per (b, n): mean + rsqrt(var+eps) over c ----------------
__global__ __launch_bounds__(256) void ln_stats_kernel(const float* __restrict__ x,
                                                       float* __restrict__ mu,
                                                       float* __restrict__ rr)
{
    int n = blockIdx.x * 256 + threadIdx.x;
    int b = blockIdx.y;
    const float* xb = x + (size_t)b * NCH * NTOK + n;
    float s = 0.f, s2 = 0.f;
    #pragma unroll 8
    for (int c = 0; c < NCH; ++c) {
        float v = xb[(size_t)c * NTOK];
        s += v;
        s2 += v * v;
    }
    float m = s * (1.0f / NCH);
    float var = s2 * (1.0f / NCH) - m * m;
    mu[b * NTOK + n] = m;
    rr[b * NTOK + n] = rsqrtf(var + LN_EPS);
}

// ---------------- QKV GEMM with fused LN on B, bf16 output ----------------
// Y[b][o][n] = sum_c W[o][c] * ((x[b][c][n]-mu[b][n])*rr[b][n]) + bias[o]
// 128x128 tile, BK=16, 256 threads, 8x8 per thread.
__global__ __launch_bounds__(256) void gemm_qkv_kernel(
    const float* __restrict__ W,     // [1536][512]
    const float* __restrict__ X,     // [B][512][4096]
    const float* __restrict__ mu,    // [B][4096]
    const float* __restrict__ rr,    // [B][4096]
    const float* __restrict__ bias,  // [1536]
    bf16_t* __restrict__ Y)          // [B][1536][4096]
{
    const int N = NTOK, K = NCH;
    int b = blockIdx.z;
    X  += (size_t)b * NCH * NTOK;
    Y  += (size_t)b * QKV_M * NTOK;
    mu += (size_t)b * NTOK;
    rr += (size_t)b * NTOK;
    int n0 = blockIdx.x * 128;
    int m0 = blockIdx.y * 128;

    __shared__ float As[16][128];   // As[k][m]
    __shared__ float Bs[16][132];   // Bs[k][n] padded

    int tid = threadIdx.x;
    int tm = tid >> 4;
    int tn = tid & 15;

    float acc[8][8];
    #pragma unroll
    for (int i = 0; i < 8; ++i)
        #pragma unroll
        for (int j = 0; j < 8; ++j) acc[i][j] = 0.f;

    int la_m = tid >> 1;
    int la_k = (tid & 1) * 8;
    int lb_k = tid >> 4;
    int lb_n = (tid & 15) * 8;

    // per-column LN params (constant across k) — hoisted
    float4 mu0 = *reinterpret_cast<const float4*>(&mu[n0 + lb_n]);
    float4 mu1 = *reinterpret_cast<const float4*>(&mu[n0 + lb_n + 4]);
    float4 rr0 = *reinterpret_cast<const float4*>(&rr[n0 + lb_n]);
    float4 rr1 = *reinterpret_cast<const float4*>(&rr[n0 + lb_n + 4]);

    for (int k0 = 0; k0 < K; k0 += 16) {
        float4 a0 = *reinterpret_cast<const float4*>(&W[(size_t)(m0 + la_m) * K + k0 + la_k]);
        float4 a1 = *reinterpret_cast<const float4*>(&W[(size_t)(m0 + la_m) * K + k0 + la_k + 4]);
        float4 b0 = *reinterpret_cast<const float4*>(&X[(size_t)(k0 + lb_k) * N + n0 + lb_n]);
        float4 b1 = *reinterpret_cast<const float4*>(&X[(size_t)(k0 + lb_k) * N + n0 + lb_n + 4]);
        b0.x = (b0.x - mu0.x) * rr0.x; b0.y = (b0.y - mu0.y) * rr0.y;
        b0.z = (b0.z - mu0.z) * rr0.z; b0.w = (b0.w - mu0.w) * rr0.w;
        b1.x = (b1.x - mu1.x) * rr1.x; b1.y = (b1.y - mu1.y) * rr1.y;
        b1.z = (b1.z - mu1.z) * rr1.z; b1.w = (b1.w - mu1.w) * rr1.w;
        __syncthreads();
        As[la_k + 0][la_m] = a0.x;
        As[la_k + 1][la_m] = a0.y;
        As[la_k + 2][la_m] = a0.z;
        As[la_k + 3][la_m] = a0.w;
        As[la_k + 4][la_m] = a1.x;
        As[la_k + 5][la_m] = a1.y;
        As[la_k + 6][la_m] = a1.z;
        As[la_k + 7][la_m] = a1.w;
        *reinterpret_cast<float4*>(&Bs[lb_k][lb_n])     = b0;
        *reinterpret_cast<float4*>(&Bs[lb_k][lb_n + 4]) = b1;
        __syncthreads();
        #pragma unroll
        for (int k = 0; k < 16; ++k) {
            float4 av0 = *reinterpret_cast<const float4*>(&As[k][tm * 4]);
            float4 av1 = *reinterpret_cast<const float4*>(&As[k][tm * 4 + 64]);
            float4 bv0 = *reinterpret_cast<const float4*>(&Bs[k][tn * 4]);
            float4 bv1 = *reinterpret_cast<const float4*>(&Bs[k][tn * 4 + 64]);
            float ar[8] = {av0.x, av0.y, av0.z, av0.w, av1.x, av1.y, av1.z, av1.w};
            float br[8] = {bv0.x, bv0.y, bv0.z, bv0.w, bv1.x, bv1.y, bv1.z, bv1.w};
            #pragma unroll
            for (int i = 0; i < 8; ++i)
                #pragma unroll
                for (int j = 0; j < 8; ++j)
                    acc[i][j] += ar[i] * br[j];
        }
    }

    #pragma unroll
    for (int i = 0; i < 8; ++i) {
        int r = m0 + tm * 4 + (i & 3) + (i >> 2) * 64;
        float bi = bias[r];
        uint2 w0, w1;
        w0.x = pack2bf(acc[i][0] + bi, acc[i][1] + bi);
        w0.y = pack2bf(acc[i][2] + bi, acc[i][3] + bi);
        w1.x = pack2bf(acc[i][4] + bi, acc[i][5] + bi);
        w1.y = pack2bf(acc[i][6] + bi, acc[i][7] + bi);
        *reinterpret_cast<uint2*>(&Y[(size_t)r * N + n0 + tn * 4])      = w0;
        *reinterpret_cast<uint2*>(&Y[(size_t)r * N + n0 + 64 + tn * 4]) = w1;
    }
}

// ---------------- output GEMM: fp32 A (wfold), bf16 B (V), fp32 out + bias ----------------
__global__ __launch_bounds__(256) void gemm_out_kernel(
    const float* __restrict__ A,     // [B][512][512]
    const bf16_t* __restrict__ V,    // [B] stride QKV_M*NTOK, rows [512][4096]
    const float* __restrict__ bias,  // [512]
    float* __restrict__ Y)           // [B][512][4096]
{
    const int N = NTOK, K = NCH;
    int b = blockIdx.z;
    A += (size_t)b * NCH * NCH;
    V += (size_t)b * QKV_M * NTOK;
    Y += (size_t)b * NCH * NTOK;
    int n0 = blockIdx.x * 128;
    int m0 = blockIdx.y * 128;

    __shared__ float As[16][128];
    __shared__ float Bs[16][132];

    int tid = threadIdx.x;
    int tm = tid >> 4;
    int tn = tid & 15;

    float acc[8][8];
    #pragma unroll
    for (int i = 0; i < 8; ++i)
        #pragma unroll
        for (int j = 0; j < 8; ++j) acc[i][j] = 0.f;

    int la_m = tid >> 1;
    int la_k = (tid & 1) * 8;
    int lb_k = tid >> 4;
    int lb_n = (tid & 15) * 8;

    for (int k0 = 0; k0 < K; k0 += 16) {
        float4 a0 = *reinterpret_cast<const float4*>(&A[(size_t)(m0 + la_m) * K + k0 + la_k]);
        float4 a1 = *reinterpret_cast<const float4*>(&A[(size_t)(m0 + la_m) * K + k0 + la_k + 4]);
        uint4 braw = *reinterpret_cast<const uint4*>(&V[(size_t)(k0 + lb_k) * N + n0 + lb_n]);
        __syncthreads();
        As[la_k + 0][la_m] = a0.x;
        As[la_k + 1][la_m] = a0.y;
        As[la_k + 2][la_m] = a0.z;
        As[la_k + 3][la_m] = a0.w;
        As[la_k + 4][la_m] = a1.x;
        As[la_k + 5][la_m] = a1.y;
        As[la_k + 6][la_m] = a1.z;
        As[la_k + 7][la_m] = a1.w;
        float4 b0, b1;
        b0.x = bf2f((bf16_t)(braw.x & 0xFFFF)); b0.y = bf2f((bf16_t)(braw.x >> 16));
        b0.z = bf2f((bf16_t)(braw.y & 0xFFFF)); b0.w = bf2f((bf16_t)(braw.y >> 16));
        b1.x = bf2f((bf16_t)(braw.z & 0xFFFF)); b1.y = bf2f((bf16_t)(braw.z >> 16));
        b1.z = bf2f((bf16_t)(braw.w & 0xFFFF)); b1.w = bf2f((bf16_t)(braw.w >> 16));
        *reinterpret_cast<float4*>(&Bs[lb_k][lb_n])     = b0;
        *reinterpret_cast<float4*>(&Bs[lb_k][lb_n + 4]) = b1;
        __syncthreads();
        #pragma unroll
        for (int k = 0; k < 16; ++k) {
            float4 av0 = *reinterpret_cast<const float4*>(&As[k][tm * 4]);
            float4 av1 = *reinterpret_cast<const float4*>(&As[k][tm * 4 + 64]);
            float4 bv0 = *reinterpret_cast<const float4*>(&Bs[k][tn * 4]);
            float4 bv1 = *reinterpret_cast<const float4*>(&Bs[k][tn * 4 + 64]);
            float ar[8] = {av0.x, av0.y, av0.z, av0.w, av1.x, av1.y, av1.z, av1.w};
            float br[8] = {bv0.x, bv0.y, bv0.z, bv0.w, bv1.x, bv1.y, bv1.z, bv1.w};
            #pragma unroll
            for (int i = 0; i < 8; ++i)
                #pragma unroll
                for (int j = 0; j < 8; ++j)
                    acc[i][j] += ar[i] * br[j];
        }
    }

    #pragma unroll
    for (int i = 0; i < 8; ++i) {
        int r = m0 + tm * 4 + (i & 3) + (i >> 2) * 64;
        float bi = bias[r];
        float4 o0 = make_float4(acc[i][0] + bi, acc[i][1] + bi, acc[i][2] + bi, acc[i][3] + bi);
        float4 o1 = make_float4(acc[i][4] + bi, acc[i][5] + bi, acc[i][6] + bi, acc[i][7] + bi);
        *reinterpret_cast<float4*>(&Y[(size_t)r * N + n0 + tn * 4])      = o0;
        *reinterpret_cast<float4*>(&Y[(size_t)r * N + n0 + 64 + tn * 4]) = o1;
    }
}

// ---------------- QK^T partial sums over token chunks (bf16 inputs) ----------------
// attn_part[chunk][bh][i][j] = sum_{n in chunk(512)} Q[b,h*64+i,n]*K[b,512+h*64+j,n]
__global__ __launch_bounds__(256) void qk_kernel(const bf16_t* __restrict__ qkvt,
                                                 float* __restrict__ attn_part)
{
    int chunk = blockIdx.x;   // 0..7
    int bh = blockIdx.y;      // 0..63
    int b = bh >> 3, h = bh & 7;
    const bf16_t* Q  = qkvt + ((size_t)b * QKV_M + h * HD) * NTOK + chunk * 512;
    const bf16_t* Kp = Q + (size_t)NCH * NTOK;

    __shared__ float Qs[64][65];
    __shared__ float Ks[64][65];

    int tid = threadIdx.x;
    int ti = tid >> 4;
    int tj = tid & 15;

    float acc[4][4];
    #pragma unroll
    for (int i = 0; i < 4; ++i)
        #pragma unroll
        for (int j = 0; j < 4; ++j) acc[i][j] = 0.f;

    int lr = tid >> 4;          // 0..15
    int lc = (tid & 15) * 4;    // 0..60

    for (int cc = 0; cc < 512; cc += 64) {
        __syncthreads();
        #pragma unroll
        for (int r = 0; r < 64; r += 16) {
            ushort4 qv = *reinterpret_cast<const ushort4*>(&Q[(size_t)(lr + r) * NTOK + cc + lc]);
            ushort4 kv = *reinterpret_cast<const ushort4*>(&Kp[(size_t)(lr + r) * NTOK + cc + lc]);
            Qs[lr + r][lc + 0] = bf2f(qv.x); Qs[lr + r][lc + 1] = bf2f(qv.y);
            Qs[lr + r][lc + 2] = bf2f(qv.z); Qs[lr + r][lc + 3] = bf2f(qv.w);
            Ks[lr + r][lc + 0] = bf2f(kv.x); Ks[lr + r][lc + 1] = bf2f(kv.y);
            Ks[lr + r][lc + 2] = bf2f(kv.z); Ks[lr + r][lc + 3] = bf2f(kv.w);
        }
        __syncthreads();
        #pragma unroll 4
        for (int kk = 0; kk < 64; ++kk) {
            float qv[4], kv[4];
            #pragma unroll
            for (int i2 = 0; i2 < 4; ++i2) qv[i2] = Qs[ti * 4 + i2][kk];
            #pragma unroll
            for (int j2 = 0; j2 < 4; ++j2) kv[j2] = Ks[tj * 4 + j2][kk];
            #pragma unroll
            for (int i2 = 0; i2 < 4; ++i2)
                #pragma unroll
                for (int j2 = 0; j2 < 4; ++j2)
                    acc[i2][j2] += qv[i2] * kv[j2];
        }
    }
    #pragma unroll
    for (int i2 = 0; i2 < 4; ++i2)
        #pragma unroll
        for (int j2 = 0; j2 < 4; ++j2)
            attn_part[(((size_t)chunk * 64 + bh) * 64 + ti * 4 + i2) * 64 + tj * 4 + j2] = acc[i2][j2];
}

// ---------------- scale + clip + softmax (row = one wave) ----------------
__global__ __launch_bounds__(256) void softmax_kernel(const float* __restrict__ attn_part,
                                                      float* __restrict__ attn)
{
    int bh = blockIdx.x;
    int wave = threadIdx.x >> 6;
    int lane = threadIdx.x & 63;
    for (int i = wave; i < 64; i += 4) {
        float s = 0.f;
        #pragma unroll
        for (int p = 0; p < 8; ++p)
            s += attn_part[(((size_t)p * 64 + bh) * 64 + i) * 64 + lane];
        s *= 0.125f;
        s = fminf(fmaxf(s, -50.f), 50.f);
        float m = s;
        #pragma unroll
        for (int off = 32; off > 0; off >>= 1) m = fmaxf(m, __shfl_xor(m, off, 64));
        float e = __expf(s - m);
        float sum = e;
        #pragma unroll
        for (int off = 32; off > 0; off >>= 1) sum += __shfl_xor(sum, off, 64);
        float p = e / sum;
        if (p != p) p = 1.0f / HD;
        attn[((size_t)bh * 64 + i) * 64 + lane] = p;
    }
}

// ---------------- fold proj_w with attn ----------------
// Wfold[b][o][h*64+j] = sum_i Pw[o][h*64+i] * attn[bh][i][j]
__global__ __launch_bounds__(256) void fold_kernel(const float* __restrict__ Pw,
                                                   const float* __restrict__ attn,
                                                   float* __restrict__ wfold)
{
    int bh = blockIdx.y;
    int b = bh >> 3, h = bh & 7;
    int o0 = blockIdx.x * 64;

    __shared__ float Ps[64][68];
    __shared__ float Am[64][68];

    int tid = threadIdx.x;
    {
        int r  = tid >> 2;
        int cq = (tid & 3) * 4;
        #pragma unroll
        for (int j = 0; j < 4; ++j) {
            int c = cq + j * 16;
            *reinterpret_cast<float4*>(&Ps[r][c]) =
                *reinterpret_cast<const float4*>(&Pw[(size_t)(o0 + r) * NCH + h * HD + c]);
            *reinterpret_cast<float4*>(&Am[r][c]) =
                *reinterpret_cast<const float4*>(&attn[((size_t)bh * 64 + r) * 64 + c]);
        }
    }
    __syncthreads();

    int to = tid >> 4;
    int tj = tid & 15;
    float acc[4][4];
    #pragma unroll
    for (int i = 0; i < 4; ++i)
        #pragma unroll
        for (int j = 0; j < 4; ++j) acc[i][j] = 0.f;

    for (int i = 0; i < 64; ++i) {
        float pv[4];
        #pragma unroll
        for (int ii = 0; ii < 4; ++ii) pv[ii] = Ps[to * 4 + ii][i];
        float4 av = *reinterpret_cast<const float4*>(&Am[i][tj * 4]);
        float avr[4] = {av.x, av.y, av.z, av.w};
        #pragma unroll
        for (int ii = 0; ii < 4; ++ii)
            #pragma unroll
            for (int jj = 0; jj < 4; ++jj)
                acc[ii][jj] += pv[ii] * avr[jj];
    }

    #pragma unroll
    for (int ii = 0; ii < 4; ++ii)
        #pragma unroll
        for (int jj = 0; jj < 4; ++jj)
            wfold[((size_t)b * NCH + o0 + to * 4 + ii) * NCH + h * HD + tj * 4 + jj] = acc[ii][jj];
}

extern "C" void kernel_launch(void* const* d_in, const int* in_sizes, int n_in,
                              void* d_out, int out_size, void* d_ws, size_t ws_size,
                              hipStream_t stream)
{
    const float* x      = (const float*)d_in[0];
    const float* qkv_w  = (const float*)d_in[1];
    const float* qkv_b  = (const float*)d_in[2];
    const float* proj_w = (const float*)d_in[3];
    const float* proj_b = (const float*)d_in[4];
    float* out = (float*)d_out;

    // workspace layout (~113 MB total):
    float* mu        = (float*)d_ws;                       // 32768 f
    float* rr        = mu + 32768;                         // 32768 f
    float* attn_part = rr + 32768;                         // 2,097,152 f
    float* attn      = attn_part + 2097152;                // 262,144 f
    float* wfold     = attn + 262144;                      // 2,097,152 f
    bf16_t* qkvt     = (bf16_t*)(wfold + 2097152);         // 50,331,648 bf16 (100.7 MB)

    // 1) LN stats
    ln_stats_kernel<<<dim3(NTOK / 256, NBATCH), 256, 0, stream>>>(x, mu, rr);

    // 2) QKV GEMM with fused LN, bf16 output: qkvt[b][o][n]
    gemm_qkv_kernel<<<dim3(NTOK / 128, QKV_M / 128, NBATCH), 256, 0, stream>>>(
        qkv_w, x, mu, rr, qkv_b, qkvt);

    // 3) QK^T partial sums over 8 token-chunks
    qk_kernel<<<dim3(8, 64), 256, 0, stream>>>(qkvt, attn_part);

    // 4) scale + clip + softmax
    softmax_kernel<<<64, 256, 0, stream>>>(attn_part, attn);

    // 5) fold proj_w into attn
    fold_kernel<<<dim3(8, 64), 256, 0, stream>>>(proj_w, attn, wfold);

    // 6) output GEMM: out[b][o][n] = sum_c wfold[b][o][c] * V[b][c][n] + proj_b[o]
    gemm_out_kernel<<<dim3(NTOK / 128, NCH / 128, NBATCH), 256, 0, stream>>>(
        wfold, qkvt + (size_t)1024 * NTOK, proj_b, out);
}

// Round 5
// 346.531 us; speedup vs baseline: 2.8524x; 2.8524x over previous
//
#include <hip/hip_runtime.h>
#include <cstddef>

#define NBATCH 8
#define NCH 512
#define NTOK 4096   // 64*64 tokens
#define NH 8
#define HD 64
#define QKV_M 1536
#define LN_EPS 1e-5f

typedef unsigned short bf16_t;
typedef __attribute__((ext_vector_type(8))) short bf16x8;   // 8 bf16 = 4 VGPR (MFMA A/B frag)
typedef __attribute__((ext_vector_type(4))) float f32x4;    // MFMA C/D frag
typedef __attribute__((ext_vector_type(8))) unsigned short us8;

__device__ __forceinline__ float bf2f(bf16_t u) {
    return __uint_as_float(((unsigned)u) << 16);
}
// round-to-nearest-even fp32 -> bf16
__device__ __forceinline__ bf16_t f2bf(float f) {
    unsigned u = __float_as_uint(f);
    u += 0x7FFFu + ((u >> 16) & 1u);
    return (bf16_t)(u >> 16);
}

__device__ __forceinline__ void gload_lds16(const void* g, void* l) {
    __builtin_amdgcn_global_load_lds(
        (const __attribute__((address_space(1))) unsigned int*)g,
        (__attribute__((address_space(3))) unsigned int*)l, 16, 0, 0);
}

// ---------------- LN stats per (b, n): mean + rsqrt(var+eps) over c ----------------
__global__ __launch_bounds__(256) void ln_stats_kernel(const float* __restrict__ x,
                                                       float* __restrict__ mu,
                                                       float* __restrict__ rr)
{
    int n = blockIdx.x * 256 + threadIdx.x;
    int b = blockIdx.y;
    const float* xb = x + (size_t)b * NCH * NTOK + n;
    float s = 0.f, s2 = 0.f;
    #pragma unroll 8
    for (int c = 0; c < NCH; ++c) {
        float v = xb[(size_t)c * NTOK];
        s += v;
        s2 += v * v;
    }
    float m = s * (1.0f / NCH);
    float var = s2 * (1.0f / NCH) - m * m;
    mu[b * NTOK + n] = m;
    rr[b * NTOK + n] = rsqrtf(var + LN_EPS);
}

// ---------------- normalize + transpose + bf16: xnt[b][n][c] ----------------
// 64n x 64c tile via LDS.
__global__ __launch_bounds__(256) void ln_tr_kernel(const float* __restrict__ x,
                                                    const float* __restrict__ mu,
                                                    const float* __restrict__ rr,
                                                    bf16_t* __restrict__ xnt)
{
    int b  = blockIdx.z;
    int n0 = blockIdx.x * 64;
    int c0 = blockIdx.y * 64;
    __shared__ float T[64][65];   // pad 65: transposed reads 2-way max

    int t = threadIdx.x;
    {
        int cl = t >> 2;
        const float* xr = x + ((size_t)b * NCH + c0 + cl) * NTOK + n0;
        #pragma unroll
        for (int it = 0; it < 4; ++it) {
            int nf = ((t & 3) + it * 4) * 4;
            float4 v = *reinterpret_cast<const float4*>(xr + nf);
            T[cl][nf + 0] = v.x; T[cl][nf + 1] = v.y;
            T[cl][nf + 2] = v.z; T[cl][nf + 3] = v.w;
        }
    }
    __syncthreads();
    int nl = t >> 2;
    int coff = (t & 3) * 16;
    float muv = mu[b * NTOK + n0 + nl];
    float rrv = rr[b * NTOK + n0 + nl];
    us8 o0, o1;
    #pragma unroll
    for (int j = 0; j < 8; ++j) o0[j] = f2bf((T[coff + j][nl] - muv) * rrv);
    #pragma unroll
    for (int j = 0; j < 8; ++j) o1[j] = f2bf((T[coff + 8 + j][nl] - muv) * rrv);
    bf16_t* orow = xnt + ((size_t)b * NTOK + n0 + nl) * NCH + c0 + coff;
    *reinterpret_cast<us8*>(orow)     = o0;
    *reinterpret_cast<us8*>(orow + 8) = o1;
}

// ---------------- fp32 -> bf16 weight conversion ----------------
__global__ __launch_bounds__(256) void wconv_kernel(const float* __restrict__ w,
                                                    bf16_t* __restrict__ wb)
{
    int i = (blockIdx.x * 256 + threadIdx.x) * 4;
    float4 v = *reinterpret_cast<const float4*>(w + i);
    ushort4 o;
    o.x = f2bf(v.x); o.y = f2bf(v.y); o.z = f2bf(v.z); o.w = f2bf(v.w);
    *reinterpret_cast<ushort4*>(wb + i) = o;
}

// ---------------- bf16 tile transpose: vt[b][n][c] = v_tmp[b][c][n] ----------------
__global__ __launch_bounds__(256) void vtr_kernel(const bf16_t* __restrict__ v_tmp,
                                                  bf16_t* __restrict__ vt)
{
    int b  = blockIdx.z;
    int n0 = blockIdx.x * 64;
    int c0 = blockIdx.y * 64;
    __shared__ bf16_t T[64][65];

    int t = threadIdx.x;
    {
        int cl = t >> 2;
        const bf16_t* vr = v_tmp + ((size_t)b * NCH + c0 + cl) * NTOK + n0;
        int nf = (t & 3) * 16;
        us8 a = *reinterpret_cast<const us8*>(vr + nf);
        us8 c = *reinterpret_cast<const us8*>(vr + nf + 8);
        #pragma unroll
        for (int j = 0; j < 8; ++j) { T[cl][nf + j] = a[j]; T[cl][nf + 8 + j] = c[j]; }
    }
    __syncthreads();
    int nl = t >> 2;
    int coff = (t & 3) * 16;
    us8 o0, o1;
    #pragma unroll
    for (int j = 0; j < 8; ++j) o0[j] = T[coff + j][nl];
    #pragma unroll
    for (int j = 0; j < 8; ++j) o1[j] = T[coff + 8 + j][nl];
    bf16_t* orow = vt + ((size_t)b * NTOK + n0 + nl) * NCH + c0 + coff;
    *reinterpret_cast<us8*>(orow)     = o0;
    *reinterpret_cast<us8*>(orow + 8) = o1;
}

// ---------------- MFMA GEMM: C[b][m][n] = sum_k A[m][k] * Bt[n][k] + bias[m] ----------------
// A: [M][K] bf16 k-contig (batch stride sAb elements). Bt: [NTOK][K] bf16 (batch stride sBb).
// 128x128 tile, BK=64, 4 waves (2x2), each wave 64x64 via 4x4 mfma_f32_16x16x32_bf16.
// LDS layout [128 rows][64 k] with XOR swizzle: 16B slot s of row r holds k-group (s ^ (r&7)).
// OUT_F32=false: bf16 output split at m=1024 (oQK rows [0,1024), oV rows [1024,1536) transposed base).
template<bool OUT_F32>
__global__ __launch_bounds__(256) void gemm_mfma_kernel(
    const bf16_t* __restrict__ A, size_t sAb,
    const bf16_t* __restrict__ Bt, size_t sBb,
    const float* __restrict__ bias,
    bf16_t* __restrict__ oQK,
    bf16_t* __restrict__ oV,
    float*  __restrict__ oF,
    int M, int K)
{
    int bz = blockIdx.z;
    A  += (size_t)bz * sAb;
    Bt += (size_t)bz * sBb;
    int n0 = blockIdx.x * 128;
    int m0 = blockIdx.y * 128;

    __shared__ __align__(16) bf16_t Als[128 * 64];
    __shared__ __align__(16) bf16_t Bls[128 * 64];

    int tid  = threadIdx.x;
    int wid  = tid >> 6;
    int lane = tid & 63;
    int wr = wid >> 1, wc = wid & 1;
    int lrow = lane & 15;
    int lkg  = lane >> 4;
    int srow = lane >> 3;   // staging: row within 8-row wave-load
    int sc8  = lane & 7;    // staging: 16B slot

    f32x4 acc[4][4];
    #pragma unroll
    for (int i = 0; i < 4; ++i)
        #pragma unroll
        for (int j = 0; j < 4; ++j)
            acc[i][j] = (f32x4){0.f, 0.f, 0.f, 0.f};

    for (int k0 = 0; k0 < K; k0 += 64) {
        // stage A and B tiles: each wave loads 32 rows of each (4 x 8-row wave-loads)
        #pragma unroll
        for (int i = 0; i < 4; ++i) {
            int r = wid * 32 + i * 8 + srow;
            int koff = k0 + ((sc8 ^ (r & 7)) << 3);   // pre-swizzled global source
            gload_lds16(A  + (size_t)(m0 + r) * K + koff, Als + (wid * 32 + i * 8) * 64);
            gload_lds16(Bt + (size_t)(n0 + r) * K + koff, Bls + (wid * 32 + i * 8) * 64);
        }
        __syncthreads();   // compiler emits vmcnt(0) drain here
        #pragma unroll
        for (int ks = 0; ks < 2; ++ks) {
            int kg = ks * 4 + lkg;
            bf16x8 af[4], bfv[4];
            #pragma unroll
            for (int i = 0; i < 4; ++i) {
                int row = wr * 64 + i * 16 + lrow;
                af[i] = *reinterpret_cast<const bf16x8*>(Als + row * 64 + ((kg ^ (row & 7)) << 3));
            }
            #pragma unroll
            for (int j = 0; j < 4; ++j) {
                int row = wc * 64 + j * 16 + lrow;
                bfv[j] = *reinterpret_cast<const bf16x8*>(Bls + row * 64 + ((kg ^ (row & 7)) << 3));
            }
            #pragma unroll
            for (int i = 0; i < 4; ++i)
                #pragma unroll
                for (int j = 0; j < 4; ++j)
                    acc[i][j] = __builtin_amdgcn_mfma_f32_16x16x32_bf16(af[i], bfv[j], acc[i][j], 0, 0, 0);
        }
        __syncthreads();
    }

    // epilogue: D element (row=(lane>>4)*4+r, col=lane&15) per 16x16 tile
    #pragma unroll
    for (int i = 0; i < 4; ++i) {
        #pragma unroll
        for (int r = 0; r < 4; ++r) {
            int m = m0 + wr * 64 + i * 16 + (lane >> 4) * 4 + r;
            float bv = bias[m];
            #pragma unroll
            for (int j = 0; j < 4; ++j) {
                int n = n0 + wc * 64 + j * 16 + (lane & 15);
                float v = acc[i][j][r] + bv;
                if (OUT_F32) {
                    oF[((size_t)bz * M + m) * NTOK + n] = v;
                } else {
                    bf16_t ob = f2bf(v);
                    if (m0 < 1024) oQK[((size_t)bz * 1024 + m) * NTOK + n] = ob;
                    else           oV[((size_t)bz * NCH + (m - 1024)) * NTOK + n] = ob;
                }
            }
        }
    }
}

// ---------------- QK^T partial sums over token chunks (bf16 inputs) ----------------
// attn_part[chunk][bh][i][j] = sum_{n in chunk(512)} Q[b,h*64+i,n]*K[b,512+h*64+j,n]
__global__ __launch_bounds__(256) void qk_kernel(const bf16_t* __restrict__ qk_buf,
                                                 float* __restrict__ attn_part)
{
    int chunk = blockIdx.x;   // 0..7
    int bh = blockIdx.y;      // 0..63
    int b = bh >> 3, h = bh & 7;
    const bf16_t* Q  = qk_buf + ((size_t)b * 1024 + h * HD) * NTOK + chunk * 512;
    const bf16_t* Kp = Q + (size_t)NCH * NTOK;

    __shared__ float Qs[64][65];
    __shared__ float Ks[64][65];

    int tid = threadIdx.x;
    int ti = tid >> 4;
    int tj = tid & 15;

    float acc[4][4];
    #pragma unroll
    for (int i = 0; i < 4; ++i)
        #pragma unroll
        for (int j = 0; j < 4; ++j) acc[i][j] = 0.f;

    int lr = tid >> 4;
    int lc = (tid & 15) * 4;

    for (int cc = 0; cc < 512; cc += 64) {
        __syncthreads();
        #pragma unroll
        for (int r = 0; r < 64; r += 16) {
            ushort4 qv = *reinterpret_cast<const ushort4*>(&Q[(size_t)(lr + r) * NTOK + cc + lc]);
            ushort4 kv = *reinterpret_cast<const ushort4*>(&Kp[(size_t)(lr + r) * NTOK + cc + lc]);
            Qs[lr + r][lc + 0] = bf2f(qv.x); Qs[lr + r][lc + 1] = bf2f(qv.y);
            Qs[lr + r][lc + 2] = bf2f(qv.z); Qs[lr + r][lc + 3] = bf2f(qv.w);
            Ks[lr + r][lc + 0] = bf2f(kv.x); Ks[lr + r][lc + 1] = bf2f(kv.y);
            Ks[lr + r][lc + 2] = bf2f(kv.z); Ks[lr + r][lc + 3] = bf2f(kv.w);
        }
        __syncthreads();
        #pragma unroll 4
        for (int kk = 0; kk < 64; ++kk) {
            float qv[4], kv[4];
            #pragma unroll
            for (int i2 = 0; i2 < 4; ++i2) qv[i2] = Qs[ti * 4 + i2][kk];
            #pragma unroll
            for (int j2 = 0; j2 < 4; ++j2) kv[j2] = Ks[tj * 4 + j2][kk];
            #pragma unroll
            for (int i2 = 0; i2 < 4; ++i2)
                #pragma unroll
                for (int j2 = 0; j2 < 4; ++j2)
                    acc[i2][j2] += qv[i2] * kv[j2];
        }
    }
    #pragma unroll
    for (int i2 = 0; i2 < 4; ++i2)
        #pragma unroll
        for (int j2 = 0; j2 < 4; ++j2)
            attn_part[(((size_t)chunk * 64 + bh) * 64 + ti * 4 + i2) * 64 + tj * 4 + j2] = acc[i2][j2];
}

// ---------------- scale + clip + softmax (row = one wave) ----------------
__global__ __launch_bounds__(256) void softmax_kernel(const float* __restrict__ attn_part,
                                                      float* __restrict__ attn)
{
    int bh = blockIdx.x;
    int wave = threadIdx.x >> 6;
    int lane = threadIdx.x & 63;
    for (int i = wave; i < 64; i += 4) {
        float s = 0.f;
        #pragma unroll
        for (int p = 0; p < 8; ++p)
            s += attn_part[(((size_t)p * 64 + bh) * 64 + i) * 64 + lane];
        s *= 0.125f;
        s = fminf(fmaxf(s, -50.f), 50.f);
        float m = s;
        #pragma unroll
        for (int off = 32; off > 0; off >>= 1) m = fmaxf(m, __shfl_xor(m, off, 64));
        float e = __expf(s - m);
        float sum = e;
        #pragma unroll
        for (int off = 32; off > 0; off >>= 1) sum += __shfl_xor(sum, off, 64);
        float p = e / sum;
        if (p != p) p = 1.0f / HD;
        attn[((size_t)bh * 64 + i) * 64 + lane] = p;
    }
}

// ---------------- fold proj_w with attn (bf16 output) ----------------
// Wfold[b][o][h*64+j] = sum_i Pw[o][h*64+i] * attn[bh][i][j]
__global__ __launch_bounds__(256) void fold_kernel(const float* __restrict__ Pw,
                                                   const float* __restrict__ attn,
                                                   bf16_t* __restrict__ wfold)
{
    int bh = blockIdx.y;
    int b = bh >> 3, h = bh & 7;
    int o0 = blockIdx.x * 64;

    __shared__ float Ps[64][68];
    __shared__ float Am[64][68];

    int tid = threadIdx.x;
    {
        int r  = tid >> 2;
        int cq = (tid & 3) * 4;
        #pragma unroll
        for (int j = 0; j < 4; ++j) {
            int c = cq + j * 16;
            *reinterpret_cast<float4*>(&Ps[r][c]) =
                *reinterpret_cast<const float4*>(&Pw[(size_t)(o0 + r) * NCH + h * HD + c]);
            *reinterpret_cast<float4*>(&Am[r][c]) =
                *reinterpret_cast<const float4*>(&attn[((size_t)bh * 64 + r) * 64 + c]);
        }
    }
    __syncthreads();

    int to = tid >> 4;
    int tj = tid & 15;
    float acc[4][4];
    #pragma unroll
    for (int i = 0; i < 4; ++i)
        #pragma unroll
        for (int j = 0; j < 4; ++j) acc[i][j] = 0.f;

    for (int i = 0; i < 64; ++i) {
        float pv[4];
        #pragma unroll
        for (int ii = 0; ii < 4; ++ii) pv[ii] = Ps[to * 4 + ii][i];
        float4 av = *reinterpret_cast<const float4*>(&Am[i][tj * 4]);
        float avr[4] = {av.x, av.y, av.z, av.w};
        #pragma unroll
        for (int ii = 0; ii < 4; ++ii)
            #pragma unroll
            for (int jj = 0; jj < 4; ++jj)
                acc[ii][jj] += pv[ii] * avr[jj];
    }

    #pragma unroll
    for (int ii = 0; ii < 4; ++ii)
        #pragma unroll
        for (int jj = 0; jj < 4; ++jj)
            wfold[((size_t)b * NCH + o0 + to * 4 + ii) * NCH + h * HD + tj * 4 + jj] = f2bf(acc[ii][jj]);
}

extern "C" void kernel_launch(void* const* d_in, const int* in_sizes, int n_in,
                              void* d_out, int out_size, void* d_ws, size_t ws_size,
                              hipStream_t stream)
{
    const float* x      = (const float*)d_in[0];
    const float* qkv_w  = (const float*)d_in[1];
    const float* qkv_b  = (const float*)d_in[2];
    const float* proj_w = (const float*)d_in[3];
    const float* proj_b = (const float*)d_in[4];
    float* out = (float*)d_out;

    // ---- workspace (~110.7 MiB) ----
    float* mu        = (float*)d_ws;                       // 32768
    float* rr        = mu + 32768;                         // 32768
    float* attn_part = rr + 32768;                         // 2,097,152
    float* attn      = attn_part + 2097152;                // 262,144
    bf16_t* wfold    = (bf16_t*)(attn + 262144);           // 8*512*512      = 2,097,152
    bf16_t* w_bf     = wfold + 2097152;                    // 1536*512       =   786,432
    bf16_t* qk_buf   = w_bf + 786432;                      // 8*1024*4096    = 33,554,432 (64 MiB)
    bf16_t* vt       = qk_buf + (size_t)33554432;          // 8*4096*512     = 16,777,216 (32 MiB)

    // ---- d_out doubles as scratch before the final GEMM (64 MiB total) ----
    bf16_t* xnt   = (bf16_t*)d_out;                        // [B][4096][512] bf16, 32 MiB, dead after QKV GEMM
    bf16_t* v_tmp = (bf16_t*)d_out + 16777216;             // [B][512][4096] bf16, 32 MiB, dead after vtr

    // 1) LN stats
    ln_stats_kernel<<<dim3(NTOK / 256, NBATCH), 256, 0, stream>>>(x, mu, rr);

    // 2) normalize + transpose + bf16: xnt[b][n][c]
    ln_tr_kernel<<<dim3(NTOK / 64, NCH / 64, NBATCH), 256, 0, stream>>>(x, mu, rr, xnt);

    // 3) qkv_w -> bf16
    wconv_kernel<<<dim3(QKV_M * NCH / 1024), 256, 0, stream>>>(qkv_w, w_bf);

    // 4) QKV GEMM (MFMA): Q,K -> qk_buf[b][0..1024)[n]; V -> v_tmp[b][c][n]
    gemm_mfma_kernel<false><<<dim3(NTOK / 128, QKV_M / 128, NBATCH), 256, 0, stream>>>(
        w_bf, 0, xnt, (size_t)NTOK * NCH, qkv_b, qk_buf, v_tmp, nullptr, QKV_M, NCH);

    // 5) V transpose: vt[b][n][c]
    vtr_kernel<<<dim3(NTOK / 64, NCH / 64, NBATCH), 256, 0, stream>>>(v_tmp, vt);

    // 6) QK^T partial sums
    qk_kernel<<<dim3(8, 64), 256, 0, stream>>>(qk_buf, attn_part);

    // 7) scale + clip + softmax
    softmax_kernel<<<64, 256, 0, stream>>>(attn_part, attn);

    // 8) fold proj_w into attn (bf16)
    fold_kernel<<<dim3(8, 64), 256, 0, stream>>>(proj_w, attn, wfold);

    // 9) output GEMM (MFMA): out[b][o][n] = sum_c wfold[o][c] * vt[n][c] + proj_b[o]
    gemm_mfma_kernel<true><<<dim3(NTOK / 128, NCH / 128, NBATCH), 256, 0, stream>>>(
        wfold, (size_t)NCH * NCH, vt, (size_t)NTOK * NCH, proj_b,
        nullptr, nullptr, out, NCH, NCH);
}

// Round 7
// 313.214 us; speedup vs baseline: 3.1558x; 1.1064x over previous
//
#include <hip/hip_runtime.h>
#include <cstddef>

#define NBATCH 8
#define NCH 512
#define NTOK 4096   // 64*64 tokens
#define NH 8
#define HD 64
#define QKV_M 1536
#define LN_EPS 1e-5f

typedef unsigned short bf16_t;
typedef __attribute__((ext_vector_type(8))) short bf16x8;   // 8 bf16 = 4 VGPR (MFMA A/B frag)
typedef __attribute__((ext_vector_type(4))) float f32x4;    // MFMA C/D frag
typedef __attribute__((ext_vector_type(8))) unsigned short us8;

__device__ __forceinline__ float bf2f(bf16_t u) {
    return __uint_as_float(((unsigned)u) << 16);
}
// round-to-nearest-even fp32 -> bf16
__device__ __forceinline__ bf16_t f2bf(float f) {
    unsigned u = __float_as_uint(f);
    u += 0x7FFFu + ((u >> 16) & 1u);
    return (bf16_t)(u >> 16);
}

__device__ __forceinline__ void gload_lds16(const void* g, void* l) {
    __builtin_amdgcn_global_load_lds(
        (const __attribute__((address_space(1))) unsigned int*)g,
        (__attribute__((address_space(3))) unsigned int*)l, 16, 0, 0);
}

// ---------------- LN stats per (b, n): mean + rsqrt(var+eps) over c ----------------
__global__ __launch_bounds__(256) void ln_stats_kernel(const float* __restrict__ x,
                                                       float* __restrict__ mu,
                                                       float* __restrict__ rr)
{
    int n = blockIdx.x * 256 + threadIdx.x;
    int b = blockIdx.y;
    const float* xb = x + (size_t)b * NCH * NTOK + n;
    float s = 0.f, s2 = 0.f;
    #pragma unroll 8
    for (int c = 0; c < NCH; ++c) {
        float v = xb[(size_t)c * NTOK];
        s += v;
        s2 += v * v;
    }
    float m = s * (1.0f / NCH);
    float var = s2 * (1.0f / NCH) - m * m;
    mu[b * NTOK + n] = m;
    rr[b * NTOK + n] = rsqrtf(var + LN_EPS);
}

// ---------------- normalize + transpose + bf16: xnt[b][n][c] ----------------
// 64n x 64c tile via LDS. x re-read is L3-hit (x = 64 MiB < 256 MiB L3).
__global__ __launch_bounds__(256) void ln_tr_kernel(const float* __restrict__ x,
                                                    const float* __restrict__ mu,
                                                    const float* __restrict__ rr,
                                                    bf16_t* __restrict__ xnt)
{
    int b  = blockIdx.z;
    int n0 = blockIdx.x * 64;
    int c0 = blockIdx.y * 64;
    __shared__ float T[64][65];   // pad 65: transposed reads 2-way max

    int t = threadIdx.x;
    {
        int cl = t >> 2;
        const float* xr = x + ((size_t)b * NCH + c0 + cl) * NTOK + n0;
        #pragma unroll
        for (int it = 0; it < 4; ++it) {
            int nf = ((t & 3) + it * 4) * 4;
            float4 v = *reinterpret_cast<const float4*>(xr + nf);
            T[cl][nf + 0] = v.x; T[cl][nf + 1] = v.y;
            T[cl][nf + 2] = v.z; T[cl][nf + 3] = v.w;
        }
    }
    __syncthreads();
    int nl = t >> 2;
    int coff = (t & 3) * 16;
    float muv = mu[b * NTOK + n0 + nl];
    float rrv = rr[b * NTOK + n0 + nl];
    us8 o0, o1;
    #pragma unroll
    for (int j = 0; j < 8; ++j) o0[j] = f2bf((T[coff + j][nl] - muv) * rrv);
    #pragma unroll
    for (int j = 0; j < 8; ++j) o1[j] = f2bf((T[coff + 8 + j][nl] - muv) * rrv);
    bf16_t* orow = xnt + ((size_t)b * NTOK + n0 + nl) * NCH + c0 + coff;
    *reinterpret_cast<us8*>(orow)     = o0;
    *reinterpret_cast<us8*>(orow + 8) = o1;
}

// ---------------- fp32 -> bf16 weight conversion ----------------
__global__ __launch_bounds__(256) void wconv_kernel(const float* __restrict__ w,
                                                    bf16_t* __restrict__ wb)
{
    int i = (blockIdx.x * 256 + threadIdx.x) * 4;
    float4 v = *reinterpret_cast<const float4*>(w + i);
    ushort4 o;
    o.x = f2bf(v.x); o.y = f2bf(v.y); o.z = f2bf(v.z); o.w = f2bf(v.w);
    *reinterpret_cast<ushort4*>(wb + i) = o;
}

// ---------------- MFMA GEMM: C[b][m][n] = sum_k A[m][k] * Bt[n][k] + bias ----------------
// A: [M][K] bf16 k-contig (batch stride sAb elems). Bt: [N][K] bf16 (batch stride sBb).
// 128x128 tile, BK=64, 4 waves (2x2), each wave 64x64 via 4x4 mfma_f32_16x16x32_bf16.
// LDS layout [128 rows][64 k], XOR swizzle: 16B slot s of row r holds k-group (s ^ (r&7)).
// BIAS_COL: bias indexed by output column (V-swap GEMM), else by row.
template<bool OUT_F32, bool BIAS_COL>
__global__ __launch_bounds__(256) void gemm_mfma_kernel(
    const bf16_t* __restrict__ A, size_t sAb,
    const bf16_t* __restrict__ Bt, size_t sBb,
    const float* __restrict__ bias,
    bf16_t* __restrict__ ob,
    float*  __restrict__ of,
    int ldC, int M, int K)
{
    int bz = blockIdx.z;
    A  += (size_t)bz * sAb;
    Bt += (size_t)bz * sBb;
    int n0 = blockIdx.x * 128;
    int m0 = blockIdx.y * 128;

    __shared__ __align__(16) bf16_t Als[128 * 64];
    __shared__ __align__(16) bf16_t Bls[128 * 64];

    int tid  = threadIdx.x;
    int wid  = tid >> 6;
    int lane = tid & 63;
    int wr = wid >> 1, wc = wid & 1;
    int lrow = lane & 15;
    int lkg  = lane >> 4;
    int srow = lane >> 3;   // staging: row within 8-row wave-load
    int sc8  = lane & 7;    // staging: 16B slot

    f32x4 acc[4][4];
    #pragma unroll
    for (int i = 0; i < 4; ++i)
        #pragma unroll
        for (int j = 0; j < 4; ++j)
            acc[i][j] = (f32x4){0.f, 0.f, 0.f, 0.f};

    for (int k0 = 0; k0 < K; k0 += 64) {
        #pragma unroll
        for (int i = 0; i < 4; ++i) {
            int r = wid * 32 + i * 8 + srow;
            int koff = k0 + ((sc8 ^ (r & 7)) << 3);   // pre-swizzled global source
            gload_lds16(A  + (size_t)(m0 + r) * K + koff, Als + (wid * 32 + i * 8) * 64);
            gload_lds16(Bt + (size_t)(n0 + r) * K + koff, Bls + (wid * 32 + i * 8) * 64);
        }
        __syncthreads();
        #pragma unroll
        for (int ks = 0; ks < 2; ++ks) {
            int kg = ks * 4 + lkg;
            bf16x8 af[4], bfv[4];
            #pragma unroll
            for (int i = 0; i < 4; ++i) {
                int row = wr * 64 + i * 16 + lrow;
                af[i] = *reinterpret_cast<const bf16x8*>(Als + row * 64 + ((kg ^ (row & 7)) << 3));
            }
            #pragma unroll
            for (int j = 0; j < 4; ++j) {
                int row = wc * 64 + j * 16 + lrow;
                bfv[j] = *reinterpret_cast<const bf16x8*>(Bls + row * 64 + ((kg ^ (row & 7)) << 3));
            }
            #pragma unroll
            for (int i = 0; i < 4; ++i)
                #pragma unroll
                for (int j = 0; j < 4; ++j)
                    acc[i][j] = __builtin_amdgcn_mfma_f32_16x16x32_bf16(af[i], bfv[j], acc[i][j], 0, 0, 0);
        }
        __syncthreads();
    }

    // epilogue: D element (row=(lane>>4)*4+r, col=lane&15) per 16x16 tile
    #pragma unroll
    for (int i = 0; i < 4; ++i) {
        #pragma unroll
        for (int r = 0; r < 4; ++r) {
            int m = m0 + wr * 64 + i * 16 + (lane >> 4) * 4 + r;
            float bvr = BIAS_COL ? 0.f : bias[m];
            #pragma unroll
            for (int j = 0; j < 4; ++j) {
                int n = n0 + wc * 64 + j * 16 + (lane & 15);
                float v = acc[i][j][r] + (BIAS_COL ? bias[n] : bvr);
                if (OUT_F32) of[((size_t)bz * M + m) * ldC + n] = v;
                else         ob[((size_t)bz * M + m) * ldC + n] = f2bf(v);
            }
        }
    }
}

// ---------------- QK^T partial sums, MFMA, direct global->VGPR frags ----------------
// attn_part[chunk][bh][i][j] = sum_{n in chunk(512)} Q[b,h*64+i,n]*K[b,512+h*64+j,n]
// 4 waves: wave w computes rows [16w,16w+16) x 64 over the chunk's 512 tokens.
__global__ __launch_bounds__(256) void qk_mfma_kernel(const bf16_t* __restrict__ qk_buf,
                                                      float* __restrict__ attn_part)
{
    int chunk = blockIdx.x;   // 0..7
    int bh = blockIdx.y;      // 0..63
    int b = bh >> 3, h = bh & 7;
    const bf16_t* Q  = qk_buf + ((size_t)b * 1024 + h * HD) * NTOK;
    const bf16_t* Kp = Q + (size_t)NCH * NTOK;

    int tid = threadIdx.x;
    int w = tid >> 6;
    int lane = tid & 63;
    int frow = lane & 15;
    int kg = lane >> 4;

    f32x4 acc[4];
    #pragma unroll
    for (int j = 0; j < 4; ++j) acc[j] = (f32x4){0.f, 0.f, 0.f, 0.f};

    const bf16_t* Qrow = Q + (size_t)(w * 16 + frow) * NTOK + chunk * 512 + kg * 8;
    const bf16_t* Krow = Kp + (size_t)frow * NTOK + chunk * 512 + kg * 8;

    for (int ks = 0; ks < 16; ++ks) {
        bf16x8 af = *reinterpret_cast<const bf16x8*>(Qrow + ks * 32);
        #pragma unroll
        for (int j = 0; j < 4; ++j) {
            bf16x8 bfv = *reinterpret_cast<const bf16x8*>(Krow + (size_t)(j * 16) * NTOK + ks * 32);
            acc[j] = __builtin_amdgcn_mfma_f32_16x16x32_bf16(af, bfv, acc[j], 0, 0, 0);
        }
    }

    #pragma unroll
    for (int j = 0; j < 4; ++j)
        #pragma unroll
        for (int r = 0; r < 4; ++r) {
            int i  = w * 16 + (lane >> 4) * 4 + r;
            int jj = j * 16 + (lane & 15);
            attn_part[(((size_t)chunk * 64 + bh) * 64 + i) * 64 + jj] = acc[j][r];
        }
}

// ---------------- scale + clip + softmax (row = one wave) ----------------
__global__ __launch_bounds__(256) void softmax_kernel(const float* __restrict__ attn_part,
                                                      float* __restrict__ attn)
{
    int bh = blockIdx.x;
    int wave = threadIdx.x >> 6;
    int lane = threadIdx.x & 63;
    for (int i = wave; i < 64; i += 4) {
        float s = 0.f;
        #pragma unroll
        for (int p = 0; p < 8; ++p)
            s += attn_part[(((size_t)p * 64 + bh) * 64 + i) * 64 + lane];
        s *= 0.125f;
        s = fminf(fmaxf(s, -50.f), 50.f);
        float m = s;
        #pragma unroll
        for (int off = 32; off > 0; off >>= 1) m = fmaxf(m, __shfl_xor(m, off, 64));
        float e = __expf(s - m);
        float sum = e;
        #pragma unroll
        for (int off = 32; off > 0; off >>= 1) sum += __shfl_xor(sum, off, 64);
        float p = e / sum;
        if (p != p) p = 1.0f / HD;
        attn[((size_t)bh * 64 + i) * 64 + lane] = p;
    }
}

// ---------------- fold proj_w with attn (bf16 output) ----------------
// Wfold[b][o][h*64+j] = sum_i Pw[o][h*64+i] * attn[bh][i][j]
__global__ __launch_bounds__(256) void fold_kernel(const float* __restrict__ Pw,
                                                   const float* __restrict__ attn,
                                                   bf16_t* __restrict__ wfold)
{
    int bh = blockIdx.y;
    int b = bh >> 3, h = bh & 7;
    int o0 = blockIdx.x * 64;

    __shared__ float Ps[64][68];
    __shared__ float Am[64][68];

    int tid = threadIdx.x;
    {
        int r  = tid >> 2;
        int cq = (tid & 3) * 4;
        #pragma unroll
        for (int j = 0; j < 4; ++j) {
            int c = cq + j * 16;
            *reinterpret_cast<float4*>(&Ps[r][c]) =
                *reinterpret_cast<const float4*>(&Pw[(size_t)(o0 + r) * NCH + h * HD + c]);
            *reinterpret_cast<float4*>(&Am[r][c]) =
                *reinterpret_cast<const float4*>(&attn[((size_t)bh * 64 + r) * 64 + c]);
        }
    }
    __syncthreads();

    int to = tid >> 4;
    int tj = tid & 15;
    float acc[4][4];
    #pragma unroll
    for (int i = 0; i < 4; ++i)
        #pragma unroll
        for (int j = 0; j < 4; ++j) acc[i][j] = 0.f;

    for (int i = 0; i < 64; ++i) {
        float pv[4];
        #pragma unroll
        for (int ii = 0; ii < 4; ++ii) pv[ii] = Ps[to * 4 + ii][i];
        float4 av = *reinterpret_cast<const float4*>(&Am[i][tj * 4]);
        float avr[4] = {av.x, av.y, av.z, av.w};
        #pragma unroll
        for (int ii = 0; ii < 4; ++ii)
            #pragma unroll
            for (int jj = 0; jj < 4; ++jj)
                acc[ii][jj] += pv[ii] * avr[jj];
    }

    #pragma unroll
    for (int ii = 0; ii < 4; ++ii)
        #pragma unroll
        for (int jj = 0; jj < 4; ++jj)
            wfold[((size_t)b * NCH + o0 + to * 4 + ii) * NCH + h * HD + tj * 4 + jj] = f2bf(acc[ii][jj]);
}

extern "C" void kernel_launch(void* const* d_in, const int* in_sizes, int n_in,
                              void* d_out, int out_size, void* d_ws, size_t ws_size,
                              hipStream_t stream)
{
    const float* x      = (const float*)d_in[0];
    const float* qkv_w  = (const float*)d_in[1];
    const float* qkv_b  = (const float*)d_in[2];
    const float* proj_w = (const float*)d_in[3];
    const float* proj_b = (const float*)d_in[4];
    float* out = (float*)d_out;

    // ---- workspace (~110.8 MiB) ----
    float* mu        = (float*)d_ws;                       // 32768
    float* rr        = mu + 32768;                         // 32768
    float* attn_part = rr + 32768;                         // 8*64*64*64   = 2,097,152
    float* attn      = attn_part + 2097152;                // 64*64*64     =   262,144
    bf16_t* wfold    = (bf16_t*)(attn + 262144);           // 8*512*512    = 2,097,152
    bf16_t* w_bf     = wfold + 2097152;                    // 1536*512     =   786,432
    bf16_t* qk_buf   = w_bf + 786432;                      // 8*1024*4096  = 33,554,432 (64 MiB)
    bf16_t* vt       = qk_buf + (size_t)33554432;          // 8*4096*512   = 16,777,216 (32 MiB)

    // ---- d_out doubles as scratch before the final GEMM ----
    bf16_t* xnt = (bf16_t*)d_out;                          // [B][4096][512] bf16, 32 MiB, dead before out-GEMM

    // 1) LN stats
    ln_stats_kernel<<<dim3(NTOK / 256, NBATCH), 256, 0, stream>>>(x, mu, rr);

    // 2) normalize + transpose + bf16: xnt[b][n][c]
    ln_tr_kernel<<<dim3(NTOK / 64, NCH / 64, NBATCH), 256, 0, stream>>>(x, mu, rr, xnt);

    // 3) qkv_w -> bf16
    wconv_kernel<<<dim3(QKV_M * NCH / 1024), 256, 0, stream>>>(qkv_w, w_bf);

    // 4a) QK GEMM (MFMA): qk_buf[b][m][n] = sum_k Wqk[m][k] * xnt[b][n][k] + qkv_b[m]
    gemm_mfma_kernel<false, false><<<dim3(NTOK / 128, 1024 / 128, NBATCH), 256, 0, stream>>>(
        w_bf, 0, xnt, (size_t)NTOK * NCH, qkv_b, qk_buf, nullptr, NTOK, 1024, NCH);

    // 4b) V GEMM swapped (MFMA): vt[b][n][c] = sum_k xnt[b][n][k] * Wv[c][k] + qkv_b[1024+c]
    gemm_mfma_kernel<false, true><<<dim3(NCH / 128, NTOK / 128, NBATCH), 256, 0, stream>>>(
        xnt, (size_t)NTOK * NCH, w_bf + (size_t)1024 * NCH, 0, qkv_b + 1024,
        vt, nullptr, NCH, NTOK, NCH);

    // 5) QK^T partial sums (MFMA, direct global frags)
    qk_mfma_kernel<<<dim3(8, 64), 256, 0, stream>>>(qk_buf, attn_part);

    // 6) scale + clip + softmax
    softmax_kernel<<<64, 256, 0, stream>>>(attn_part, attn);

    // 7) fold proj_w into attn (bf16)
    fold_kernel<<<dim3(8, 64), 256, 0, stream>>>(proj_w, attn, wfold);

    // 8) output GEMM (MFMA): out[b][o][n] = sum_c wfold[o][c] * vt[n][c] + proj_b[o]
    gemm_mfma_kernel<true, false><<<dim3(NTOK / 128, NCH / 128, NBATCH), 256, 0, stream>>>(
        wfold, (size_t)NCH * NCH, vt, (size_t)NTOK * NCH, proj_b,
        nullptr, out, NTOK, NCH, NCH);
}